// Round 5
// baseline (788.476 us; speedup 1.0000x reference)
//
#include <hip/hip_runtime.h>
#include <utility>

using u16 = unsigned short;
using u32 = unsigned int;

typedef float  f32x4  __attribute__((ext_vector_type(4)));
typedef __bf16 bf16x8 __attribute__((ext_vector_type(8)));

#define DI __device__ __forceinline__

// ------------------------------------------------------------------
// Compile-time monomial basis tables.
// Basis monomials over x[0..15]: cubic multisets (816), quadratic (136),
// linear (16). Group action: index rotation by +4q mod 16 (q=0..3).
// All cubic orbits have size 4 -> 204 reps; quad -> 36 reps; linear -> 4.
// Rep list padded to 248 = 31 chunks * 8.
// Feature slot f = chunk*32 + q*8 + j  <->  rep r = chunk*8 + j, monomial
// = rot_{4q}(rep[r]).  Lane (quad q) holds x rotated by 4q in registers,
// so all lanes execute identical compile-time-indexed code.
// ------------------------------------------------------------------
struct RepT { unsigned char a, b, c, t; };   // t: 3=cubic 2=quad 1=linear 0=null
struct Tables {
  RepT rep[248];
  short inv3[4096];
  short inv2[256];
  short inv1[16];
  int n3, n2, n1;
};

constexpr int csort3key(int w, int x, int i) {
  int a = w, b = x, c = i, t = 0;
  if (a > b) { t = a; a = b; b = t; }
  if (b > c) { t = b; b = c; c = t; }
  if (a > b) { t = a; a = b; b = t; }
  return (a << 8) | (b << 4) | c;
}

constexpr Tables build_tables() {
  Tables T = {};
  for (int i = 0; i < 4096; i++) T.inv3[i] = -1;
  for (int i = 0; i < 256; i++)  T.inv2[i] = -1;
  for (int i = 0; i < 16; i++)   T.inv1[i] = -1;
  int nr = 0;
  // cubic multisets a<=b<=c, canonical = lex-min over the 4 rotations
  for (int a = 0; a < 16; a++) for (int b = a; b < 16; b++) for (int c = b; c < 16; c++) {
    int key = (a << 8) | (b << 4) | c;
    int keys[4] = {0, 0, 0, 0};
    bool canon = true;
    for (int q = 0; q < 4; q++) {
      keys[q] = csort3key((a + 4 * q) & 15, (b + 4 * q) & 15, (c + 4 * q) & 15);
      if (keys[q] < key) canon = false;
    }
    if (!canon) continue;
    for (int q = 0; q < 4; q++) if (T.inv3[keys[q]] < 0) T.inv3[keys[q]] = (short)(nr * 4 + q);
    T.rep[nr].a = (unsigned char)a; T.rep[nr].b = (unsigned char)b;
    T.rep[nr].c = (unsigned char)c; T.rep[nr].t = 3; nr++;
  }
  T.n3 = nr;
  // quadratic multisets a<=b (size-2 orbits: duplicate slots keep S row 0)
  for (int a = 0; a < 16; a++) for (int b = a; b < 16; b++) {
    int key = (a << 4) | b;
    int keys[4] = {0, 0, 0, 0};
    bool canon = true;
    for (int q = 0; q < 4; q++) {
      int aa = (a + 4 * q) & 15, bb = (b + 4 * q) & 15;
      if (aa > bb) { int t = aa; aa = bb; bb = t; }
      keys[q] = (aa << 4) | bb;
      if (keys[q] < key) canon = false;
    }
    if (!canon) continue;
    for (int q = 0; q < 4; q++) if (T.inv2[keys[q]] < 0) T.inv2[keys[q]] = (short)(nr * 4 + q);
    T.rep[nr].a = (unsigned char)a; T.rep[nr].b = (unsigned char)b;
    T.rep[nr].c = 0; T.rep[nr].t = 2; nr++;
  }
  T.n2 = nr;
  // linear: reps 0..3
  for (int a = 0; a < 4; a++) {
    for (int q = 0; q < 4; q++) { int w = (a + 4 * q) & 15; if (T.inv1[w] < 0) T.inv1[w] = (short)(nr * 4 + q); }
    T.rep[nr].a = (unsigned char)a; T.rep[nr].b = 0; T.rep[nr].c = 0; T.rep[nr].t = 1; nr++;
  }
  T.n1 = nr;
  for (; nr < 248; nr++) { T.rep[nr].a = 0; T.rep[nr].b = 0; T.rep[nr].c = 0; T.rep[nr].t = 0; }
  return T;
}

constexpr Tables TT = build_tables();
static_assert(TT.n3 == 204, "cubic rep count");
static_assert(TT.n2 == 240, "quad rep count");
static_assert(TT.n1 == 244, "linear rep count");

__device__ const Tables g_TT = build_tables();   // runtime-indexed copy for scatter kernel

// dims
#define BN 5888
#define CN 128
#define LN 16
#define EN 10
#define NCHUNK 31          // 248 reps / 8
#define NPATH 32           // 23 + 4 + 1 padded
#define SF_ELEMS (NCHUNK * 32 * NPATH)      // 992*32 fp32 scratch in ws

DI u16 f2bf(float f) { union { __bf16 h; u16 s; } u; u.h = (__bf16)f; return u.s; }

// ------------------------------------------------------------------
// scatter kernel (multi-block, global atomics into zeroed ws):
// symmetrize U3/U2/U1 into S[feature-slot][path].
// ------------------------------------------------------------------
__global__ void scatter_kernel(const float* __restrict__ U3, const float* __restrict__ U2,
                               const float* __restrict__ U1, float* __restrict__ Sf) {
  const int tid = blockIdx.x * 256 + threadIdx.x;
  if (tid < 4096) {
    const int w = tid >> 8, xx = (tid >> 4) & 15, i = tid & 15;
    int a = w, b = xx, c = i, t;
    if (a > b) { t = a; a = b; b = t; }
    if (b > c) { t = b; b = c; c = t; }
    if (a > b) { t = a; a = b; b = t; }
    const int rq = g_TT.inv3[(a << 8) | (b << 4) | c];
    const int r = rq >> 2, q = rq & 3;
    const int f = (r >> 3) * 32 + q * 8 + (r & 7);
    for (int k = 0; k < 23; k++) {
      const float v = U3[tid * 23 + k];
      if (v != 0.f) atomicAdd(&Sf[f * NPATH + k], v);
    }
  } else if (tid < 4096 + 256) {
    const int t2 = tid - 4096;
    const int w = t2 >> 4, xx = t2 & 15;
    const int a = w < xx ? w : xx, b = w < xx ? xx : w;
    const int rq = g_TT.inv2[(a << 4) | b];
    const int r = rq >> 2, q = rq & 3;
    const int f = (r >> 3) * 32 + q * 8 + (r & 7);
    for (int k = 0; k < 4; k++) {
      const float v = U2[t2 * 4 + k];
      if (v != 0.f) atomicAdd(&Sf[f * NPATH + 23 + k], v);
    }
  } else if (tid < 4096 + 256 + 16) {
    const int w = tid - (4096 + 256);
    const int rq = g_TT.inv1[w];
    const int r = rq >> 2, q = rq & 3;
    const int f = (r >> 3) * 32 + q * 8 + (r & 7);
    const float v = U1[w];
    if (v != 0.f) atomicAdd(&Sf[f * NPATH + 27], v);
  }
}

// ------------------------------------------------------------------
// main kernel
// ------------------------------------------------------------------
template<int R>
DI float featf(const float* xr) {
  constexpr RepT rp = TT.rep[R];
  if constexpr (rp.t == 3) return xr[rp.a] * xr[rp.b] * xr[rp.c];
  else if constexpr (rp.t == 2) return xr[rp.a] * xr[rp.b];
  else if constexpr (rp.t == 1) return xr[rp.a];
  else return 0.f;
}

template<int C>
DI bf16x8 make_B(const float* xr) {
  bf16x8 r;
  r[0] = (__bf16)featf<C * 8 + 0>(xr);
  r[1] = (__bf16)featf<C * 8 + 1>(xr);
  r[2] = (__bf16)featf<C * 8 + 2>(xr);
  r[3] = (__bf16)featf<C * 8 + 3>(xr);
  r[4] = (__bf16)featf<C * 8 + 4>(xr);
  r[5] = (__bf16)featf<C * 8 + 5>(xr);
  r[6] = (__bf16)featf<C * 8 + 6>(xr);
  r[7] = (__bf16)featf<C * 8 + 7>(xr);
  return r;
}

// one pair-tile per wave: live state ~50 VGPRs -> zero spills at the
// allocator's 64-VGPR target for 1024-thread blocks (verified round 4:
// VGPR=44, WRITE_SIZE = output only).
template<int C>
DI void chunk_step(const uint4* sf, int lane, const float* xr,
                   f32x4& a0, f32x4& a1) {
  const bf16x8 A0 = *reinterpret_cast<const bf16x8*>(sf + (C * 2 + 0) * 64 + lane);
  const bf16x8 A1 = *reinterpret_cast<const bf16x8*>(sf + (C * 2 + 1) * 64 + lane);
  const bf16x8 B = make_B<C>(xr);
  a0 = __builtin_amdgcn_mfma_f32_16x16x32_bf16(A0, B, a0, 0, 0, 0);
  a1 = __builtin_amdgcn_mfma_f32_16x16x32_bf16(A1, B, a1, 0, 0, 0);
}

template<int... Cs>
DI void all_chunks(std::integer_sequence<int, Cs...>, const uint4* sf, int lane,
                   const float* xr, f32x4& a0, f32x4& a1) {
  (chunk_step<Cs>(sf, lane, xr, a0, a1), ...);
}

// load 16 fp32 x-values of `pair`, rotated by 4q at the ADDRESS level:
// xr[v] = x[pair][(v + 4q) & 15]
DI void load_xr(const float* __restrict__ x, int pair, int q, float* xr) {
  const float* base = x + pair * 16;
#pragma unroll
  for (int u = 0; u < 4; u++) {
    const int g = (u + q) & 3;
    const float4 v = *(const float4*)(base + g * 4);
    xr[u * 4 + 0] = v.x;
    xr[u * 4 + 1] = v.y;
    xr[u * 4 + 2] = v.z;
    xr[u * 4 + 3] = v.w;
  }
}

// LDS = sfrag only (62 KB) -> 2 blocks/CU = 32 waves/CU even with
// runtime-reserved LDS (round 4's 78 KB apparently fell back to 1 block/CU:
// OccupancyPercent 38).  WB is computed inline in the epilogue (8 paths x
// 10 elements per lane) instead of a block-wide LDS phase.
__global__ __launch_bounds__(1024) void main_kernel(
    const float* __restrict__ x, const float* __restrict__ y,
    const float* __restrict__ w3, const float* __restrict__ w2, const float* __restrict__ w1,
    const float* __restrict__ Sf, float* __restrict__ out)
{
  __shared__ uint4 sfrag[NCHUNK * 2 * 64];     // 62 KB: S in A-frag order
  const int tid = threadIdx.x;

  // stage S: read fp32 S from ws, convert+pack to bf16 A-fragment order.
  // block (chunk,pathtile) of 64 lanes, lane l -> 16B bf16
  // S^T[path = P*16 + (l&15)][feat = c*32 + (l>>4)*8 + 0..7]
  for (int idx = tid; idx < NCHUNK * 2 * 64; idx += 1024) {
    const int cp = idx >> 6, l = idx & 63;
    const int c = cp >> 1, P = cp & 1;
    const int path = P * 16 + (l & 15);
    const int fbase = c * 32 + (l >> 4) * 8;
    u32 d[4];
#pragma unroll
    for (int h = 0; h < 4; h++) {
      const u32 lo = f2bf(Sf[(fbase + 2 * h)     * NPATH + path]);
      const u32 hi = f2bf(Sf[(fbase + 2 * h + 1) * NPATH + path]);
      d[h] = lo | (hi << 16);
    }
    uint4 o; o.x = d[0]; o.y = d[1]; o.z = d[2]; o.w = d[3];
    sfrag[idx] = o;
  }
  __syncthreads();

  // wave handles 16 pairs (1 pair-tile); block = 256 pairs = 2 b's
  const int wv = tid >> 6, lane = tid & 63;
  const int q = lane >> 4, n = lane & 15;
  const int pair0 = blockIdx.x * 256 + wv * 16 + n;
  const int bidx = pair0 >> 7;     // node index (wave-uniform)
  const int cc   = pair0 & 127;    // channel

  float xr[16];
  load_xr(x, pair0, q, xr);

  f32x4 a0 = {0.f, 0.f, 0.f, 0.f};
  f32x4 a1 = a0;
  all_chunks(std::make_integer_sequence<int, NCHUNK>{}, sfrag, lane, xr, a0, a1);

  // epilogue: D layout (16x16x32): col = lane&15 = pair, row = path.
  // This lane needs paths pA = q*4+rg (always w3) and pB = 16+q*4+rg
  // (w3 / w2 / w1 / zero-pad).  wb[p] = sum_e y[b][e] * w[e][p][cc].
  const float* baseB[4]; int strB[4]; float mskB[4];
#pragma unroll
  for (int rg = 0; rg < 4; rg++) {
    const int pB = 16 + q * 4 + rg;
    if (pB < 23)      { baseB[rg] = w3 + pB * 128 + cc;        strB[rg] = 23 * 128; mskB[rg] = 1.f; }
    else if (pB < 27) { baseB[rg] = w2 + (pB - 23) * 128 + cc; strB[rg] = 4 * 128;  mskB[rg] = 1.f; }
    else if (pB == 27){ baseB[rg] = w1 + cc;                   strB[rg] = 128;      mskB[rg] = 1.f; }
    else              { baseB[rg] = w1 + cc;                   strB[rg] = 128;      mskB[rg] = 0.f; }
  }
  float wbA[4] = {0.f, 0.f, 0.f, 0.f}, wbB[4] = {0.f, 0.f, 0.f, 0.f};
#pragma unroll
  for (int e = 0; e < EN; e++) {
    const float ye = y[bidx * EN + e];
#pragma unroll
    for (int rg = 0; rg < 4; rg++) {
      wbA[rg] += ye * w3[(e * 23 + q * 4 + rg) * 128 + cc];
      wbB[rg] += ye * baseB[rg][e * strB[rg]];
    }
  }
  float p0 = 0.f;
#pragma unroll
  for (int rg = 0; rg < 4; rg++)
    p0 += a0[rg] * wbA[rg] + a1[rg] * (wbB[rg] * mskB[rg]);
  p0 += __shfl_xor(p0, 16);
  p0 += __shfl_xor(p0, 32);
  if (q == 0) out[pair0] = p0;
}

// ------------------------------------------------------------------
extern "C" void kernel_launch(void* const* d_in, const int* in_sizes, int n_in,
                              void* d_out, int out_size, void* d_ws, size_t ws_size,
                              hipStream_t stream) {
  const float* x  = (const float*)d_in[0];
  const float* y  = (const float*)d_in[1];
  const float* U3 = (const float*)d_in[2];
  const float* U2 = (const float*)d_in[3];
  const float* U1 = (const float*)d_in[4];
  const float* w3 = (const float*)d_in[5];
  const float* w2 = (const float*)d_in[6];
  const float* w1 = (const float*)d_in[7];
  float* Sf  = (float*)d_ws;
  float* out = (float*)d_out;

  hipMemsetAsync(Sf, 0, SF_ELEMS * sizeof(float), stream);
  hipLaunchKernelGGL(scatter_kernel, dim3(18),   dim3(256),  0, stream, U3, U2, U1, Sf);
  hipLaunchKernelGGL(main_kernel,    dim3(2944), dim3(1024), 0, stream,
                     x, y, w3, w2, w1, Sf, out);
}

// Round 6
// 196.321 us; speedup vs baseline: 4.0163x; 4.0163x over previous
//
#include <hip/hip_runtime.h>
#include <utility>

using u16 = unsigned short;
using u32 = unsigned int;

typedef float  f32x4  __attribute__((ext_vector_type(4)));
typedef __bf16 bf16x8 __attribute__((ext_vector_type(8)));

#define DI __device__ __forceinline__

// ------------------------------------------------------------------
// Compile-time monomial basis tables.
// Basis monomials over x[0..15]: cubic multisets (816), quadratic (136),
// linear (16). Group action: index rotation by +4q mod 16 (q=0..3).
// All cubic orbits have size 4 -> 204 reps; quad -> 36 reps; linear -> 4.
// Rep list padded to 248 = 31 chunks * 8.
// Feature slot f = chunk*32 + q*8 + j  <->  rep r = chunk*8 + j, monomial
// = rot_{4q}(rep[r]).  Lane (quad q) holds x rotated by 4q in registers,
// so all lanes execute identical compile-time-indexed code.
// ------------------------------------------------------------------
struct RepT { unsigned char a, b, c, t; };   // t: 3=cubic 2=quad 1=linear 0=null
struct Tables {
  RepT rep[248];
  short inv3[4096];
  short inv2[256];
  short inv1[16];
  int n3, n2, n1;
};

constexpr int csort3key(int w, int x, int i) {
  int a = w, b = x, c = i, t = 0;
  if (a > b) { t = a; a = b; b = t; }
  if (b > c) { t = b; b = c; c = t; }
  if (a > b) { t = a; a = b; b = t; }
  return (a << 8) | (b << 4) | c;
}

constexpr Tables build_tables() {
  Tables T = {};
  for (int i = 0; i < 4096; i++) T.inv3[i] = -1;
  for (int i = 0; i < 256; i++)  T.inv2[i] = -1;
  for (int i = 0; i < 16; i++)   T.inv1[i] = -1;
  int nr = 0;
  // cubic multisets a<=b<=c, canonical = lex-min over the 4 rotations
  for (int a = 0; a < 16; a++) for (int b = a; b < 16; b++) for (int c = b; c < 16; c++) {
    int key = (a << 8) | (b << 4) | c;
    int keys[4] = {0, 0, 0, 0};
    bool canon = true;
    for (int q = 0; q < 4; q++) {
      keys[q] = csort3key((a + 4 * q) & 15, (b + 4 * q) & 15, (c + 4 * q) & 15);
      if (keys[q] < key) canon = false;
    }
    if (!canon) continue;
    for (int q = 0; q < 4; q++) if (T.inv3[keys[q]] < 0) T.inv3[keys[q]] = (short)(nr * 4 + q);
    T.rep[nr].a = (unsigned char)a; T.rep[nr].b = (unsigned char)b;
    T.rep[nr].c = (unsigned char)c; T.rep[nr].t = 3; nr++;
  }
  T.n3 = nr;
  // quadratic multisets a<=b (size-2 orbits: duplicate slots keep S row 0)
  for (int a = 0; a < 16; a++) for (int b = a; b < 16; b++) {
    int key = (a << 4) | b;
    int keys[4] = {0, 0, 0, 0};
    bool canon = true;
    for (int q = 0; q < 4; q++) {
      int aa = (a + 4 * q) & 15, bb = (b + 4 * q) & 15;
      if (aa > bb) { int t = aa; aa = bb; bb = t; }
      keys[q] = (aa << 4) | bb;
      if (keys[q] < key) canon = false;
    }
    if (!canon) continue;
    for (int q = 0; q < 4; q++) if (T.inv2[keys[q]] < 0) T.inv2[keys[q]] = (short)(nr * 4 + q);
    T.rep[nr].a = (unsigned char)a; T.rep[nr].b = (unsigned char)b;
    T.rep[nr].c = 0; T.rep[nr].t = 2; nr++;
  }
  T.n2 = nr;
  // linear: reps 0..3
  for (int a = 0; a < 4; a++) {
    for (int q = 0; q < 4; q++) { int w = (a + 4 * q) & 15; if (T.inv1[w] < 0) T.inv1[w] = (short)(nr * 4 + q); }
    T.rep[nr].a = (unsigned char)a; T.rep[nr].b = 0; T.rep[nr].c = 0; T.rep[nr].t = 1; nr++;
  }
  T.n1 = nr;
  for (; nr < 248; nr++) { T.rep[nr].a = 0; T.rep[nr].b = 0; T.rep[nr].c = 0; T.rep[nr].t = 0; }
  return T;
}

constexpr Tables TT = build_tables();
static_assert(TT.n3 == 204, "cubic rep count");
static_assert(TT.n2 == 240, "quad rep count");
static_assert(TT.n1 == 244, "linear rep count");

__device__ const Tables g_TT = build_tables();   // runtime-indexed copy for scatter kernel

// dims
#define BN 5888
#define CN 128
#define LN 16
#define EN 10
#define NCHUNK 31          // 248 reps / 8
#define NPATH 32           // 23 + 4 + 1 padded
#define SF_ELEMS (NCHUNK * 32 * NPATH)      // 992*32 fp32 scratch in ws

DI u16 f2bf(float f) { union { __bf16 h; u16 s; } u; u.h = (__bf16)f; return u.s; }
DI float bf2f(u16 v) { union { u32 u; float f; } w; w.u = ((u32)v) << 16; return w.f; }

// ------------------------------------------------------------------
// scatter kernel: one thread per (U-element, path). Global atomics into
// zeroed ws. ~4.8k nonzero atomics total, spread over 373 blocks.
// ------------------------------------------------------------------
#define N3WORK (4096 * 23)
#define N2WORK (256 * 4)
#define NWORK  (N3WORK + N2WORK + 16)

__global__ void scatter_kernel(const float* __restrict__ U3, const float* __restrict__ U2,
                               const float* __restrict__ U1, float* __restrict__ Sf) {
  const int tid = blockIdx.x * 256 + threadIdx.x;
  if (tid >= NWORK) return;
  if (tid < N3WORK) {
    const int item = tid / 23, k = tid - item * 23;
    const float v = U3[tid];
    if (v == 0.f) return;
    const int w = item >> 8, xx = (item >> 4) & 15, i = item & 15;
    int a = w, b = xx, c = i, t;
    if (a > b) { t = a; a = b; b = t; }
    if (b > c) { t = b; b = c; c = t; }
    if (a > b) { t = a; a = b; b = t; }
    const int rq = g_TT.inv3[(a << 8) | (b << 4) | c];
    const int r = rq >> 2, q = rq & 3;
    const int f = (r >> 3) * 32 + q * 8 + (r & 7);
    atomicAdd(&Sf[f * NPATH + k], v);
  } else if (tid < N3WORK + N2WORK) {
    const int t2 = tid - N3WORK;
    const int item = t2 >> 2, k = t2 & 3;
    const float v = U2[t2];
    if (v == 0.f) return;
    const int w = item >> 4, xx = item & 15;
    const int a = w < xx ? w : xx, b = w < xx ? xx : w;
    const int rq = g_TT.inv2[(a << 4) | b];
    const int r = rq >> 2, q = rq & 3;
    const int f = (r >> 3) * 32 + q * 8 + (r & 7);
    atomicAdd(&Sf[f * NPATH + 23 + k], v);
  } else {
    const int w = tid - (N3WORK + N2WORK);
    const float v = U1[w];
    if (v == 0.f) return;
    const int rq = g_TT.inv1[w];
    const int r = rq >> 2, q = rq & 3;
    const int f = (r >> 3) * 32 + q * 8 + (r & 7);
    atomicAdd(&Sf[f * NPATH + 27], v);
  }
}

// ------------------------------------------------------------------
// main kernel
// ------------------------------------------------------------------
template<int R>
DI float featf(const float* xr) {
  constexpr RepT rp = TT.rep[R];
  if constexpr (rp.t == 3) return xr[rp.a] * xr[rp.b] * xr[rp.c];
  else if constexpr (rp.t == 2) return xr[rp.a] * xr[rp.b];
  else if constexpr (rp.t == 1) return xr[rp.a];
  else return 0.f;
}

template<int C>
DI bf16x8 make_B(const float* xr) {
  bf16x8 r;
  r[0] = (__bf16)featf<C * 8 + 0>(xr);
  r[1] = (__bf16)featf<C * 8 + 1>(xr);
  r[2] = (__bf16)featf<C * 8 + 2>(xr);
  r[3] = (__bf16)featf<C * 8 + 3>(xr);
  r[4] = (__bf16)featf<C * 8 + 4>(xr);
  r[5] = (__bf16)featf<C * 8 + 5>(xr);
  r[6] = (__bf16)featf<C * 8 + 6>(xr);
  r[7] = (__bf16)featf<C * 8 + 7>(xr);
  return r;
}

// one pair-tile per wave: live state ~50 VGPRs -> zero spills at the
// allocator's 64-VGPR target for 1024-thread blocks (round 4: VGPR=44,
// WRITE_SIZE = output only, main 125 us).
template<int C>
DI void chunk_step(const uint4* sf, int lane, const float* xr,
                   f32x4& a0, f32x4& a1) {
  const bf16x8 A0 = *reinterpret_cast<const bf16x8*>(sf + (C * 2 + 0) * 64 + lane);
  const bf16x8 A1 = *reinterpret_cast<const bf16x8*>(sf + (C * 2 + 1) * 64 + lane);
  const bf16x8 B = make_B<C>(xr);
  a0 = __builtin_amdgcn_mfma_f32_16x16x32_bf16(A0, B, a0, 0, 0, 0);
  a1 = __builtin_amdgcn_mfma_f32_16x16x32_bf16(A1, B, a1, 0, 0, 0);
}

template<int... Cs>
DI void all_chunks(std::integer_sequence<int, Cs...>, const uint4* sf, int lane,
                   const float* xr, f32x4& a0, f32x4& a1) {
  (chunk_step<Cs>(sf, lane, xr, a0, a1), ...);
}

// load 16 fp32 x-values of `pair`, rotated by 4q at the ADDRESS level:
// xr[v] = x[pair][(v + 4q) & 15]
DI void load_xr(const float* __restrict__ x, int pair, int q, float* xr) {
  const float* base = x + pair * 16;
#pragma unroll
  for (int u = 0; u < 4; u++) {
    const int g = (u + q) & 3;
    const float4 v = *(const float4*)(base + g * 4);
    xr[u * 4 + 0] = v.x;
    xr[u * 4 + 1] = v.y;
    xr[u * 4 + 2] = v.z;
    xr[u * 4 + 3] = v.w;
  }
}

// WB MUST be computed block-cooperatively into LDS with coalesced w-reads:
// round 5's per-lane inline w-loads thrashed L2 (x streaming evicts the
// 138 KB w arrays) -> 990 MB HBM fetch, 766 us.  LDS total 78 KB.
__global__ __launch_bounds__(1024) void main_kernel(
    const float* __restrict__ x, const float* __restrict__ y,
    const float* __restrict__ w3, const float* __restrict__ w2, const float* __restrict__ w1,
    const float* __restrict__ Sf, float* __restrict__ out)
{
  __shared__ uint4 sfrag[NCHUNK * 2 * 64];     // 62 KB: S in A-frag order
  __shared__ u16  wbl[2 * 32 * 128];           // 16 KB: WB[bb][path][c] bf16
  const int tid = threadIdx.x;

  // stage S: read fp32 S from ws, convert+pack to bf16 A-fragment order.
  // block (chunk,pathtile) of 64 lanes, lane l -> 16B bf16
  // S^T[path = P*16 + (l&15)][feat = c*32 + (l>>4)*8 + 0..7]
  for (int idx = tid; idx < NCHUNK * 2 * 64; idx += 1024) {
    const int cp = idx >> 6, l = idx & 63;
    const int c = cp >> 1, P = cp & 1;
    const int path = P * 16 + (l & 15);
    const int fbase = c * 32 + (l >> 4) * 8;
    u32 d[4];
#pragma unroll
    for (int h = 0; h < 4; h++) {
      const u32 lo = f2bf(Sf[(fbase + 2 * h)     * NPATH + path]);
      const u32 hi = f2bf(Sf[(fbase + 2 * h + 1) * NPATH + path]);
      d[h] = lo | (hi << 16);
    }
    uint4 o; o.x = d[0]; o.y = d[1]; o.z = d[2]; o.w = d[3];
    sfrag[idx] = o;
  }

  // per-block WB = y @ concat(w3,w2,w1): block covers 2 consecutive b's.
  // thread t -> bb = t>>9, p = (t>>4)&31, c-octet = (t&15)*8 : exactly 1024.
  const int b0 = blockIdx.x * 2;
  {
    const int bb = tid >> 9;
    const int p  = (tid >> 4) & 31;
    const int c0 = (tid & 15) * 8;
    float yv[EN];
#pragma unroll
    for (int e = 0; e < EN; e++) yv[e] = y[(b0 + bb) * EN + e];
    float acc[8];
#pragma unroll
    for (int m = 0; m < 8; m++) acc[m] = 0.f;
    const float* wsrc = nullptr; int stride = 0;
    if (p < 23)       { wsrc = w3 + p * 128;        stride = 23 * 128; }
    else if (p < 27)  { wsrc = w2 + (p - 23) * 128; stride = 4 * 128; }
    else if (p == 27) { wsrc = w1;                  stride = 128; }
    if (wsrc) {
      for (int e = 0; e < EN; e++) {
        const float* src = wsrc + e * stride + c0;
        const float4 v0 = *(const float4*)(src);
        const float4 v1 = *(const float4*)(src + 4);
        acc[0] += yv[e] * v0.x; acc[1] += yv[e] * v0.y;
        acc[2] += yv[e] * v0.z; acc[3] += yv[e] * v0.w;
        acc[4] += yv[e] * v1.x; acc[5] += yv[e] * v1.y;
        acc[6] += yv[e] * v1.z; acc[7] += yv[e] * v1.w;
      }
    }
#pragma unroll
    for (int m = 0; m < 8; m++) wbl[bb * 4096 + p * 128 + c0 + m] = f2bf(acc[m]);
  }
  __syncthreads();

  // wave handles 16 pairs (1 pair-tile); block = 256 pairs = 2 b's exactly
  const int wv = tid >> 6, lane = tid & 63;
  const int q = lane >> 4, n = lane & 15;
  const int pair0 = blockIdx.x * 256 + wv * 16 + n;

  float xr[16];
  load_xr(x, pair0, q, xr);

  f32x4 a0 = {0.f, 0.f, 0.f, 0.f};
  f32x4 a1 = a0;
  all_chunks(std::make_integer_sequence<int, NCHUNK>{}, sfrag, lane, xr, a0, a1);

  // epilogue: out[pair] = sum_p D[p][pair] * WB[b][p][c], reduce over quads.
  // D layout (16x16x32): col = lane&15 = pair, row = q*4+reg = path.
  const int bbw = wv >> 3;                 // waves 0-7 -> b0, 8-15 -> b0+1
  const int cc  = (wv & 7) * 16 + n;       // = pair0 % 128 = channel
  float p0 = 0.f;
#pragma unroll
  for (int rg = 0; rg < 4; rg++) {
    p0 += a0[rg] * bf2f(wbl[bbw * 4096 + (q * 4 + rg) * 128 + cc]);
    p0 += a1[rg] * bf2f(wbl[bbw * 4096 + (16 + q * 4 + rg) * 128 + cc]);
  }
  p0 += __shfl_xor(p0, 16);
  p0 += __shfl_xor(p0, 32);
  if (q == 0) out[pair0] = p0;
}

// ------------------------------------------------------------------
extern "C" void kernel_launch(void* const* d_in, const int* in_sizes, int n_in,
                              void* d_out, int out_size, void* d_ws, size_t ws_size,
                              hipStream_t stream) {
  const float* x  = (const float*)d_in[0];
  const float* y  = (const float*)d_in[1];
  const float* U3 = (const float*)d_in[2];
  const float* U2 = (const float*)d_in[3];
  const float* U1 = (const float*)d_in[4];
  const float* w3 = (const float*)d_in[5];
  const float* w2 = (const float*)d_in[6];
  const float* w1 = (const float*)d_in[7];
  float* Sf  = (float*)d_ws;
  float* out = (float*)d_out;

  hipMemsetAsync(Sf, 0, SF_ELEMS * sizeof(float), stream);
  hipLaunchKernelGGL(scatter_kernel, dim3((NWORK + 255) / 256), dim3(256), 0, stream,
                     U3, U2, U1, Sf);
  hipLaunchKernelGGL(main_kernel, dim3(2944), dim3(1024), 0, stream,
                     x, y, w3, w2, w1, Sf, out);
}